// Round 19
// baseline (362.929 us; speedup 1.0000x reference)
//
#include <hip/hip_runtime.h>

typedef float f32x4 __attribute__((ext_vector_type(4)));
typedef short s16x8 __attribute__((ext_vector_type(8)));
typedef unsigned short u16;
typedef u16 u16x4 __attribute__((ext_vector_type(4)));

#define SEQ 2048
#define BATCH 2
#define NH 16
#define DH 128
#define DM 2048
#define MROWS (BATCH * SEQ)  // 4096

// 1/sqrt(128) * log2(e)  (softmax done in exp2 domain)
__device__ constexpr float SCALE2 = 0.12751879523531f;

__device__ __forceinline__ u16 f2bf(float f) {
  unsigned u = __float_as_uint(f);
  u += 0x7fffu + ((u >> 16) & 1u);
  return (u16)(u >> 16);
}
__device__ __forceinline__ float bf2f(u16 b) {
  return __uint_as_float(((unsigned)b) << 16);
}

__device__ __forceinline__ void gld_lds16(const void* g, void* l) {
  __builtin_amdgcn_global_load_lds(
      (const __attribute__((address_space(1))) unsigned int*)g,
      (__attribute__((address_space(3))) unsigned int*)l, 16, 0, 0);
}

// ---------------- fused cast f32 -> bf16 (x, Wq|Wk|Wv concat, Wo) ----------
__global__ __launch_bounds__(256) void cast_all(const float* __restrict__ x,
                                                const float* __restrict__ Wq,
                                                const float* __restrict__ Wk,
                                                const float* __restrict__ Wv,
                                                const float* __restrict__ Wo,
                                                u16* __restrict__ xb,
                                                u16* __restrict__ Wqkvb,
                                                u16* __restrict__ Wob) {
  long i = (long)blockIdx.x * 256 + threadIdx.x;  // float4-group index
  const float* src;
  u16* dst;
  long off;
  if (i < 2097152)      { src = x;  dst = xb;              off = i; }
  else if (i < 3145728) { src = Wq; dst = Wqkvb;           off = i - 2097152; }
  else if (i < 4194304) { src = Wk; dst = Wqkvb + 4194304; off = i - 3145728; }
  else if (i < 5242880) { src = Wv; dst = Wqkvb + 8388608; off = i - 4194304; }
  else                  { src = Wo; dst = Wob;             off = i - 5242880; }
  float4 v = ((const float4*)src)[off];
  u16x4 o;
  o[0] = f2bf(v.x); o[1] = f2bf(v.y); o[2] = f2bf(v.z); o[3] = f2bf(v.w);
  ((u16x4*)dst)[off] = o;
}

// ============ v4 GEMM body: BM=256 x BN=128, 3-buffer pipelined =============
// Fragment reads for tile t+1 are issued in tile t AFTER the barrier and
// drained by the NEXT tile's lgkmcnt — read latency hides under MFMA(kk1).
// 3 LDS buffers (48 KB each, 144 KB total, 1 block/CU as before); stages 2
// tiles ahead, vmcnt(6) counted (never 0 in steady state). Two register
// fragment sets alternate via unroll-by-2 (compile-time indices).
// B-fragment column permute: col = wn*32 + (nf&1)*16 + (nf>>1)*64 + r.

#define BCOL(NF) (wn * 32 + ((NF) & 1) * 16 + ((NF) >> 1) * 64 + r)

#define STAGE6(TA, P) do {                                                    \
  _Pragma("unroll") for (int m_ = 0; m_ < 4; ++m_) {                          \
    const int row0_ = m_ * 64 + wave * 8;                                     \
    gld_lds16(Amat + (long)(m0 + row0_ + lrow) * 2048 + (TA) * 64 + csrc * 8, \
              &(P)[row0_ * 64]);                                              \
  }                                                                           \
  _Pragma("unroll") for (int n_ = 0; n_ < 2; ++n_) {                          \
    const int row0_ = n_ * 64 + wave * 8;                                     \
    gld_lds16(Bmat + (long)(n0 + row0_ + lrow) * 2048 + (TA) * 64 + csrc * 8, \
              &(P)[16384 + row0_ * 64]);                                      \
  } } while (0)

#define READ_SET(KK, AF, BF, P) do {                                          \
  _Pragma("unroll") for (int mf = 0; mf < 4; ++mf) {                          \
    const int arow = wm * 64 + mf * 16 + r;                                   \
    AF[KK][mf] = *(const s16x8*)&(P)[arow * 64 +                              \
                                     ((((KK) * 4 + g) ^ (arow & 7)) * 8)];    \
  }                                                                           \
  _Pragma("unroll") for (int nf = 0; nf < 4; ++nf) {                          \
    const int brow = BCOL(nf);                                                \
    BF[KK][nf] = *(const s16x8*)&(P)[16384 + brow * 64 +                      \
                                     ((((KK) * 4 + g) ^ (brow & 7)) * 8)];    \
  } } while (0)

#define MFMA_SET(KK, AF, BF) do {                                             \
  __builtin_amdgcn_s_setprio(1);                                              \
  _Pragma("unroll") for (int mf = 0; mf < 4; ++mf)                            \
    _Pragma("unroll") for (int nf = 0; nf < 4; ++nf)                          \
      acc[mf][nf] = __builtin_amdgcn_mfma_f32_16x16x32_bf16(                  \
          AF[KK][mf], BF[KK][nf], acc[mf][nf], 0, 0, 0);                      \
  __builtin_amdgcn_s_setprio(0);                                              \
} while (0)

#define TILE(T, AFC, BFC, AFN, BFN) do {                                      \
  asm volatile("s_waitcnt lgkmcnt(8)" ::: "memory");                          \
  __builtin_amdgcn_sched_barrier(0);                                          \
  MFMA_SET(0, AFC, BFC);                                                      \
  if ((T) < 30) STAGE6((T) + 2, pb2);                                         \
  asm volatile("s_waitcnt lgkmcnt(0)" ::: "memory");                          \
  __builtin_amdgcn_sched_barrier(0);                                          \
  if ((T) < 30)       asm volatile("s_waitcnt vmcnt(6)" ::: "memory");        \
  else if ((T) == 30) asm volatile("s_waitcnt vmcnt(0)" ::: "memory");        \
  __builtin_amdgcn_s_barrier();                                               \
  if ((T) < 31) {                                                             \
    READ_SET(0, AFN, BFN, pb1);                                               \
    __builtin_amdgcn_sched_barrier(0);                                        \
    READ_SET(1, AFN, BFN, pb1);                                               \
  }                                                                           \
  MFMA_SET(1, AFC, BFC);                                                      \
  { u16* tmp_ = pb0; pb0 = pb1; pb1 = pb2; pb2 = tmp_; }                      \
} while (0)

#define GEMM_V4_BODY(AIN, BIN)                                                \
  __shared__ u16 SMEM[73728]; /* 3 x 48 KB = 144 KB */                        \
  const u16* Amat = (AIN);                                                    \
  const u16* Bmat = (BIN);                                                    \
  const int tid = threadIdx.x, wave = tid >> 6, lane = tid & 63;              \
  const int r = lane & 15, g = lane >> 4;                                     \
  const int wm = wave >> 1, wn = wave & 1;                                    \
  const int bid = blockIdx.x;                                                 \
  const int swz = (bid & 7) * (gridDim.x >> 3) + (bid >> 3);                  \
  const int m0 = (swz & 15) * 256;                                            \
  const int n0 = (swz >> 4) * 128;                                            \
  const int lrow = lane >> 3;                                                 \
  const int csrc = (lane & 7) ^ lrow;                                         \
  u16 *pb0 = SMEM, *pb1 = SMEM + 24576, *pb2 = SMEM + 49152;                  \
  f32x4 acc[4][4] = {};                                                       \
  s16x8 aF0[2][4], bF0[2][4], aF1[2][4], bF1[2][4];                           \
  STAGE6(0, pb0);                                                             \
  STAGE6(1, pb1);                                                             \
  asm volatile("s_waitcnt vmcnt(6)" ::: "memory");                            \
  __builtin_amdgcn_s_barrier();                                               \
  READ_SET(0, aF0, bF0, pb0);                                                 \
  __builtin_amdgcn_sched_barrier(0);                                          \
  READ_SET(1, aF0, bF0, pb0);                                                 \
  for (int t = 0; t < 32; t += 2) {                                           \
    TILE(t,     aF0, bF0, aF1, bF1);                                          \
    TILE(t + 1, aF1, bF1, aF0, bF0);                                          \
  }

// ---------------- QKV GEMM (grid 768 = 3 exact rounds) ---------------------
// Q/K blocks (n0<4096): RoPE applied IN REGISTERS (fragment pair nf, nf+2
// holds d, d+64 in the same lane; cos[d]==cos[d+64]). V blocks: transpose
// fused via LDS T[128][256] (chunk-swizzled), coalesced stores into Vt.
__global__ __launch_bounds__(512, 1) void gemm_qkv8(const u16* __restrict__ A,
                                                    const u16* __restrict__ B,
                                                    const float* __restrict__ cosT,
                                                    const float* __restrict__ sinT,
                                                    u16* __restrict__ Qo,
                                                    u16* __restrict__ Ko,
                                                    u16* __restrict__ Vt) {
  GEMM_V4_BODY(A, B)
  if (n0 < 4096) {
    // ---- register RoPE epilogue ----
    u16* Cb = (n0 < 2048) ? Qo : Ko;
    const int nc0 = n0 & 2047;
#pragma unroll
    for (int mi = 0; mi < 4; ++mi)
#pragma unroll
      for (int nf = 0; nf < 2; ++nf) {
        const int dlo = wn * 32 + nf * 16 + r;  // in [0,64)
#pragma unroll
        for (int q = 0; q < 4; ++q) {
          const int row = m0 + wm * 64 + mi * 16 + g * 4 + q;
          const int spos = row & 2047;
          const float c = cosT[spos * 128 + dlo];
          const float s = sinT[spos * 128 + dlo];
          const float vlo = acc[mi][nf][q];
          const float vhi = acc[mi][nf + 2][q];
          Cb[(long)row * 2048 + nc0 + dlo]      = f2bf(vlo * c - vhi * s);
          Cb[(long)row * 2048 + nc0 + dlo + 64] = f2bf(vhi * c + vlo * s);
        }
      }
  } else {
    // ---- fused V transpose ----
    __syncthreads();  // main-loop LDS fully consumed
    u16* T = SMEM;    // 128 x 256 u16 = 64 KB
#pragma unroll
    for (int mi = 0; mi < 4; ++mi)
#pragma unroll
      for (int ni = 0; ni < 4; ++ni) {
        const int d = BCOL(ni);
        const int sb = wm * 64 + mi * 16 + g * 4;
        u16x4 w;
#pragma unroll
        for (int q = 0; q < 4; ++q) w[q] = f2bf(acc[mi][ni][q]);
        *(u16x4*)&T[d * 256 + (((sb >> 3) ^ (d & 7)) << 3) + (sb & 7)] = w;
      }
    __syncthreads();
    const int b_ = m0 >> 11, s0l = m0 & 2047;
    const int hh = (n0 - 4096) >> 7;
    const int dd = tid >> 2, part = tid & 3;
    u16* vrow = Vt + ((long)((b_ * 16 + hh) * 128 + dd)) * 2048 + s0l;
#pragma unroll
    for (int cc = 0; cc < 8; ++cc) {
      const int chunk = cc * 4 + part;  // consecutive tids -> consecutive 16B
      s16x8 v = *(const s16x8*)&T[dd * 256 + ((chunk ^ (dd & 7)) << 3)];
      *(s16x8*)&vrow[chunk * 8] = v;
    }
  }
}

// ---------------- Wo GEMM (grid 256 = 1 exact round, f32 out) --------------
__global__ __launch_bounds__(512, 1) void gemm_wo(const u16* __restrict__ A,
                                                  const u16* __restrict__ B,
                                                  float* __restrict__ C) {
  GEMM_V4_BODY(A, B)
#pragma unroll
  for (int mi = 0; mi < 4; ++mi)
#pragma unroll
    for (int ni = 0; ni < 4; ++ni) {
      const int col = n0 + BCOL(ni);
#pragma unroll
      for (int q = 0; q < 4; ++q)
        C[(long)(m0 + wm * 64 + mi * 16 + g * 4 + q) * 2048 + col] =
            acc[mi][ni][q];
    }
}

#undef GEMM_V4_BODY
#undef TILE
#undef MFMA_SET
#undef READ_SET
#undef STAGE6
#undef BCOL

// ---------------- Flash attention v8 (verified ~80 us, rounds 15-18) -------
// Double-buffered issue-early staging, one barrier/tile, shuffle-based
// alpha/1-over-l redistribution; mirror strips + jp-complement + XCD pin.

__device__ __forceinline__ float softmax_swapped(
    f32x4 (&s)[4], float& mi, float& li,
    u16 (&pl)[16][64], int qbase, int k0, int r, int g) {
  const int q = qbase + r;
  const bool edge = (k0 + 63) > qbase;
  float v[16];
#pragma unroll
  for (int kk = 0; kk < 4; kk++)
#pragma unroll
    for (int i = 0; i < 4; i++) {
      float x = s[kk][i] * SCALE2;
      if (edge && (k0 + kk * 16 + g * 4 + i > q)) x = -1e30f;
      v[kk * 4 + i] = x;
    }
  float t8[8], t4[4];
#pragma unroll
  for (int j = 0; j < 8; j++) t8[j] = fmaxf(v[2 * j], v[2 * j + 1]);
#pragma unroll
  for (int j = 0; j < 4; j++) t4[j] = fmaxf(t8[2 * j], t8[2 * j + 1]);
  float mx = fmaxf(fmaxf(t4[0], t4[1]), fmaxf(t4[2], t4[3]));
  mx = fmaxf(mx, __shfl_xor(mx, 16, 64));
  mx = fmaxf(mx, __shfl_xor(mx, 32, 64));
  const float mnew = fmaxf(mi, mx);
  const float a = exp2f(mi - mnew);
  float p[16];
#pragma unroll
  for (int j = 0; j < 16; j++) p[j] = exp2f(v[j] - mnew);
  float s8[8], s4[4];
#pragma unroll
  for (int j = 0; j < 8; j++) s8[j] = p[2 * j] + p[2 * j + 1];
#pragma unroll
  for (int j = 0; j < 4; j++) s4[j] = s8[2 * j] + s8[2 * j + 1];
  float ps = (s4[0] + s4[1]) + (s4[2] + s4[3]);
  ps += __shfl_xor(ps, 16, 64);
  ps += __shfl_xor(ps, 32, 64);
  li = li * a + ps;
  mi = mnew;
  const int sw = (r & 7) << 3;
#pragma unroll
  for (int kk = 0; kk < 4; kk++) {
    u16x4 w;
#pragma unroll
    for (int i = 0; i < 4; i++) w[i] = f2bf(p[kk * 4 + i]);
    *(u16x4*)&pl[r][(kk * 16 + g * 4) ^ sw] = w;
  }
  return a;
}

__global__ __launch_bounds__(512, 4) void attn_kernel(const u16* __restrict__ Q,
                                                      const u16* __restrict__ K,
                                                      const u16* __restrict__ Vt,
                                                      u16* __restrict__ O) {
  __shared__ u16 Klds[2][64 * 128];   // 2 x 16 KB, source-swizzled
  __shared__ u16 Vlds[2][128 * 64];   // 2 x 16 KB, source-swizzled
  __shared__ u16 Plds[8][16][64];     // 16 KB        (total: 80 KB exactly)

  const int tid = threadIdx.x, wave = tid >> 6, lane = tid & 63;
  const int r = lane & 15, g = lane >> 4;
  const int bh = blockIdx.x & 31;   // XCD pin: all blocks of (b,h) on bh%8
  const int jj = blockIdx.x >> 5;   // 0..15
  const int j = (jj < 8) ? jj : 23 - jj;  // complement pairing across rounds
  const int h = bh & 15, b = bh >> 4;
  const bool isB = wave >= 4;
  const int w4 = wave & 3;
  const int strip = isB ? (31 - j) : j;
  const int q0 = strip * 64 + w4 * 16;
  const int nt = 32 - j;            // staged tiles: kt = 0..31-j
  const int lastA = j;              // A-waves compute while kt <= j

  const u16* Qbh = Q + (long)b * SEQ * DM + h * DH;
  const u16* Kbh = K + (long)b * SEQ * DM + h * DH;
  const u16* Vbh = Vt + ((long)(b * NH + h)) * DH * SEQ;

  s16x8 qf[4];
#pragma unroll
  for (int jq = 0; jq < 4; jq++)
    qf[jq] = *(const s16x8*)&Qbh[(long)(q0 + r) * DM + jq * 32 + g * 8];

  f32x4 oacc[8] = {};
  float mi = -1e30f, li = 0.f;

#define STAGE_KV(KT, BU) do {                                                 \
  const int k0_ = (KT) * 64;                                                  \
  _Pragma("unroll") for (int c = 0; c < 2; ++c) {                             \
    const int s = c * 512 + tid;                                              \
    const int krow = s >> 4;                                                  \
    const int kch = (s & 15) ^ (krow & 7);                                    \
    gld_lds16(Kbh + (long)(k0_ + krow) * DM + kch * 8,                        \
              &Klds[BU][(c * 512 + wave * 64) * 8]);                          \
    const int vrow = s >> 3;                                                  \
    const int vch = (s & 7) ^ (vrow & 7);                                     \
    gld_lds16(Vbh + (long)vrow * SEQ + k0_ + vch * 8,                         \
              &Vlds[BU][(c * 512 + wave * 64) * 8]);                          \
  } } while (0)

  STAGE_KV(0, 0);
  __syncthreads();   // drains vmcnt: tile 0 ready

  for (int kt = 0; kt < nt; ++kt) {
    const int bu = kt & 1;
    if (kt + 1 < nt) STAGE_KV(kt + 1, bu ^ 1);  // issue early, wait late
    const int k0 = kt * 64;
    const u16* Kb = Klds[bu];
    const u16* Vb = Vlds[bu];

    const bool active = isB || (kt <= lastA);
    if (active) {
      // ---- QK^T (swapped: K as A-operand) ----
      f32x4 sacc[4] = {};
#pragma unroll
      for (int kk = 0; kk < 4; kk++) {
#pragma unroll
        for (int jq = 0; jq < 4; jq++) {
          s16x8 kf = *(const s16x8*)&Kb[(kk * 16 + r) * 128 +
                                        (((jq * 4 + g) ^ (r & 7)) * 8)];
          sacc[kk] = __builtin_amdgcn_mfma_f32_16x16x32_bf16(kf, qf[jq], sacc[kk], 0, 0, 0);
        }
      }
      float a = softmax_swapped(sacc, mi, li, Plds[wave], q0, k0, r, g);
      f32x4 av;
#pragma unroll
      for (int i = 0; i < 4; i++) av[i] = __shfl(a, g * 4 + i, 64);
#pragma unroll
      for (int f = 0; f < 8; f++)
#pragma unroll
        for (int i = 0; i < 4; i++) oacc[f][i] *= av[i];

      const int sw = (r & 7) << 3;
#pragma unroll
      for (int kc = 0; kc < 2; kc++) {
        s16x8 pf = *(const s16x8*)&Plds[wave][r][(kc * 32 + g * 8) ^ sw];
#pragma unroll
        for (int f = 0; f < 8; f++) {
          s16x8 vf = *(const s16x8*)&Vb[(f * 16 + r) * 64 +
                                        (((kc * 4 + g) ^ (r & 7)) * 8)];
          oacc[f] = __builtin_amdgcn_mfma_f32_16x16x32_bf16(pf, vf, oacc[f], 0, 0, 0);
        }
      }
    }
    // one barrier per tile: next tile's loads drained + WAR for buf reuse
    __syncthreads();
  }
#undef STAGE_KV

  // ---- epilogue: 1/li redistributed via shuffle, direct O write ----
  const float inv = 1.f / li;
  f32x4 iv;
#pragma unroll
  for (int i = 0; i < 4; i++) iv[i] = __shfl(inv, g * 4 + i, 64);
  u16* Obh = O + (long)b * SEQ * DM + h * DH;
#pragma unroll
  for (int f = 0; f < 8; f++)
#pragma unroll
    for (int i = 0; i < 4; i++)
      Obh[(long)(q0 + g * 4 + i) * DM + f * 16 + r] = f2bf(oacc[f][i] * iv[i]);
}

// ---------------- launch ----------------------------------------------------
extern "C" void kernel_launch(void* const* d_in, const int* in_sizes, int n_in,
                              void* d_out, int out_size, void* d_ws, size_t ws_size,
                              hipStream_t stream) {
  const float* x    = (const float*)d_in[0];
  const float* Wq   = (const float*)d_in[1];
  const float* Wk   = (const float*)d_in[2];
  const float* Wv   = (const float*)d_in[3];
  const float* Wo   = (const float*)d_in[4];
  const float* cosT = (const float*)d_in[5];
  const float* sinT = (const float*)d_in[6];
  // d_in[7] = mask: causal, applied analytically.

  if (ws_size < (size_t)134217728) return;  // need 128 MB scratch

  char* ws = (char*)d_ws;
  u16* xb    = (u16*)(ws);               // 16 MB
  u16* Wqkvb = (u16*)(ws + 16777216);    // 24 MB [Wq;Wk;Wv] rows
  u16* Wob   = (u16*)(ws + 41943040);    //  8 MB
  u16* Qlin  = (u16*)(ws + 50331648);    // 16 MB (RoPE'd by QKV GEMM)
  u16* Klin  = (u16*)(ws + 67108864);    // 16 MB (RoPE'd by QKV GEMM)
  u16* Vt    = (u16*)(ws + 100663296);   // 16 MB (transposed by QKV GEMM)
  u16* Olin  = (u16*)(ws + 117440512);   // 16 MB

  cast_all<<<24576, 256, 0, stream>>>(x, Wq, Wk, Wv, Wo, xb, Wqkvb, Wob);

  gemm_qkv8<<<768, 512, 0, stream>>>(xb, Wqkvb, cosT, sinT, Qlin, Klin, Vt);

  attn_kernel<<<512, 512, 0, stream>>>(Qlin, Klin, Vt, Olin);

  gemm_wo<<<256, 512, 0, stream>>>(Olin, Wob, (float*)d_out);
}

// Round 20
// 247.687 us; speedup vs baseline: 1.4653x; 1.4653x over previous
//
#include <hip/hip_runtime.h>

typedef float f32x4 __attribute__((ext_vector_type(4)));
typedef short s16x8 __attribute__((ext_vector_type(8)));
typedef unsigned short u16;
typedef u16 u16x4 __attribute__((ext_vector_type(4)));

#define SEQ 2048
#define BATCH 2
#define NH 16
#define DH 128
#define DM 2048
#define MROWS (BATCH * SEQ)  // 4096

// 1/sqrt(128) * log2(e)  (softmax done in exp2 domain)
__device__ constexpr float SCALE2 = 0.12751879523531f;

__device__ __forceinline__ u16 f2bf(float f) {
  unsigned u = __float_as_uint(f);
  u += 0x7fffu + ((u >> 16) & 1u);
  return (u16)(u >> 16);
}
__device__ __forceinline__ float bf2f(u16 b) {
  return __uint_as_float(((unsigned)b) << 16);
}

__device__ __forceinline__ void gld_lds16(const void* g, void* l) {
  __builtin_amdgcn_global_load_lds(
      (const __attribute__((address_space(1))) unsigned int*)g,
      (__attribute__((address_space(3))) unsigned int*)l, 16, 0, 0);
}

// ---------------- fused cast f32 -> bf16 (x, Wq|Wk|Wv concat, Wo) ----------
__global__ __launch_bounds__(256) void cast_all(const float* __restrict__ x,
                                                const float* __restrict__ Wq,
                                                const float* __restrict__ Wk,
                                                const float* __restrict__ Wv,
                                                const float* __restrict__ Wo,
                                                u16* __restrict__ xb,
                                                u16* __restrict__ Wqkvb,
                                                u16* __restrict__ Wob) {
  long i = (long)blockIdx.x * 256 + threadIdx.x;  // float4-group index
  const float* src;
  u16* dst;
  long off;
  if (i < 2097152)      { src = x;  dst = xb;              off = i; }
  else if (i < 3145728) { src = Wq; dst = Wqkvb;           off = i - 2097152; }
  else if (i < 4194304) { src = Wk; dst = Wqkvb + 4194304; off = i - 3145728; }
  else if (i < 5242880) { src = Wv; dst = Wqkvb + 8388608; off = i - 4194304; }
  else                  { src = Wo; dst = Wob;             off = i - 5242880; }
  float4 v = ((const float4*)src)[off];
  u16x4 o;
  o[0] = f2bf(v.x); o[1] = f2bf(v.y); o[2] = f2bf(v.z); o[3] = f2bf(v.w);
  ((u16x4*)dst)[off] = o;
}

// ============ shared v3 GEMM body: BM=256 x BN=128, kk-split =================
// (verified structure: 110 us for N=6144 / 3 rounds, ~941 TF — the measured
// ceiling for this family; 8-phase, dedup'd and 3-buffer pipelined variants
// all regressed: rounds 7, 8, 19.)
// B-fragment -> output-column mapping permuted: col = wn*32 + (nf&1)*16 +
// (nf>>1)*64 + r (RoPE partner d^64 sits in fragment nf^2, same lane).

#define BCOL(NF) (wn * 32 + ((NF) & 1) * 16 + ((NF) >> 1) * 64 + r)

#define GEMM_V3_BODY(A, B)                                                    \
  __shared__ u16 SMEM[49152]; /* 96 KB */                                     \
  u16 (*Alds)[16384] = (u16(*)[16384])SMEM;          /* 2 x 32 KB */          \
  u16 (*Blds)[8192]  = (u16(*)[8192])(SMEM + 32768); /* 2 x 16 KB */          \
  const int tid = threadIdx.x, wave = tid >> 6, lane = tid & 63;              \
  const int r = lane & 15, g = lane >> 4;                                     \
  const int wm = wave >> 1, wn = wave & 1;                                    \
  const int bid = blockIdx.x;                                                 \
  const int swz = (bid & 7) * (gridDim.x >> 3) + (bid >> 3);                  \
  const int m0 = (swz & 15) * 256;                                            \
  const int n0 = (swz >> 4) * 128;                                            \
  const int lrow = lane >> 3;                                                 \
  const int csrc = (lane & 7) ^ lrow;                                         \
  f32x4 acc[4][4] = {};                                                       \
  s16x8 aF[2][4], bF[2][4];                                                   \
  STAGE_A(0, 0, 0); STAGE_B(0, 0, 0); STAGE_A(0, 1, 0); STAGE_B(0, 1, 0);     \
  STAGE_A(1, 0, 1); STAGE_B(1, 0, 1);                                         \
  asm volatile("s_waitcnt vmcnt(3)" ::: "memory");                            \
  __builtin_amdgcn_s_barrier();                                               \
  for (int t = 0; t < 32; ++t) {                                              \
    const int bt = t & 1, bn = bt ^ 1;                                        \
    const u16* Ab = Alds[bt];                                                 \
    const u16* Bb = Blds[bt];                                                 \
    READ_K(0);                                                                \
    __builtin_amdgcn_sched_barrier(0);                                        \
    READ_K(1);                                                                \
    if (t < 31) { STAGE_A(t + 1, 1, bn); STAGE_B(t + 1, 1, bn); }             \
    asm volatile("s_waitcnt lgkmcnt(8)" ::: "memory");                        \
    __builtin_amdgcn_sched_barrier(0);                                        \
    MFMA_K(0);                                                                \
    asm volatile("s_waitcnt lgkmcnt(0)" ::: "memory");                        \
    __builtin_amdgcn_sched_barrier(0);                                        \
    __builtin_amdgcn_s_barrier();                                             \
    if (t < 30) { STAGE_A(t + 2, 0, bt); STAGE_B(t + 2, 0, bt); }             \
    MFMA_K(1);                                                                \
    if (t < 30)       asm volatile("s_waitcnt vmcnt(3)" ::: "memory");        \
    else if (t == 30) asm volatile("s_waitcnt vmcnt(0)" ::: "memory");        \
    __builtin_amdgcn_s_barrier();                                             \
  }

#define STAGE_A(TA, MH, BUF) do {                                             \
  _Pragma("unroll") for (int i_ = 0; i_ < 2; ++i_) {                          \
    const int row0_ = (MH) * 128 + i_ * 64 + wave * 8;                        \
    gld_lds16(A + (long)(m0 + row0_ + lrow) * 2048 + (TA) * 64 + csrc * 8,    \
              &Alds[BUF][row0_ * 64]);                                        \
  } } while (0)
#define STAGE_B(TA, NHh, BUF) do {                                            \
    const int row0_ = (NHh) * 64 + wave * 8;                                  \
    gld_lds16(B + (long)(n0 + row0_ + lrow) * 2048 + (TA) * 64 + csrc * 8,    \
              &Blds[BUF][row0_ * 64]);                                        \
  } while (0)
#define READ_K(KK) do {                                                       \
  _Pragma("unroll") for (int mf = 0; mf < 4; ++mf) {                          \
    const int arow = wm * 64 + mf * 16 + r;                                   \
    aF[KK][mf] = *(const s16x8*)&Ab[arow * 64 +                               \
                                    ((((KK) * 4 + g) ^ (arow & 7)) * 8)];     \
  }                                                                           \
  _Pragma("unroll") for (int nf = 0; nf < 4; ++nf) {                          \
    const int brow = BCOL(nf);                                                \
    bF[KK][nf] = *(const s16x8*)&Bb[brow * 64 +                               \
                                    ((((KK) * 4 + g) ^ (brow & 7)) * 8)];     \
  } } while (0)
#define MFMA_K(KK) do {                                                       \
  __builtin_amdgcn_s_setprio(1);                                              \
  _Pragma("unroll") for (int mf = 0; mf < 4; ++mf)                            \
    _Pragma("unroll") for (int nf = 0; nf < 4; ++nf)                          \
      acc[mf][nf] = __builtin_amdgcn_mfma_f32_16x16x32_bf16(                  \
          aF[KK][mf], bF[KK][nf], acc[mf][nf], 0, 0, 0);                      \
  __builtin_amdgcn_s_setprio(0);                                              \
} while (0)

// ---------------- QKV GEMM (grid 768 = 3 exact rounds) ---------------------
// Q/K blocks (n0<4096): RoPE applied IN REGISTERS in the epilogue — fragment
// pair (nf, nf+2) holds (d, d+64) in the same lane; cos[d]==cos[d+64] so one
// table read per pair. V blocks (n0>=4096): transpose fused via LDS
// T[128][256] (chunk-swizzled), 64B-coalesced stores into Vt[b,h,d,s].
__global__ __launch_bounds__(512, 2) void gemm_qkv8(const u16* __restrict__ A,
                                                    const u16* __restrict__ B,
                                                    const float* __restrict__ cosT,
                                                    const float* __restrict__ sinT,
                                                    u16* __restrict__ Qo,
                                                    u16* __restrict__ Ko,
                                                    u16* __restrict__ Vt) {
  GEMM_V3_BODY(A, B)
  if (n0 < 4096) {
    // ---- register RoPE epilogue ----
    u16* Cb = (n0 < 2048) ? Qo : Ko;
    const int nc0 = n0 & 2047;
#pragma unroll
    for (int mi = 0; mi < 4; ++mi)
#pragma unroll
      for (int nf = 0; nf < 2; ++nf) {
        const int dlo = wn * 32 + nf * 16 + r;  // in [0,64)
#pragma unroll
        for (int q = 0; q < 4; ++q) {
          const int row = m0 + wm * 64 + mi * 16 + g * 4 + q;
          const int spos = row & 2047;
          const float c = cosT[spos * 128 + dlo];
          const float s = sinT[spos * 128 + dlo];
          const float vlo = acc[mi][nf][q];
          const float vhi = acc[mi][nf + 2][q];
          Cb[(long)row * 2048 + nc0 + dlo]      = f2bf(vlo * c - vhi * s);
          Cb[(long)row * 2048 + nc0 + dlo + 64] = f2bf(vhi * c + vlo * s);
        }
      }
  } else {
    // ---- fused V transpose ----
    u16* T = SMEM;  // 128 x 256 u16 = 64 KB
#pragma unroll
    for (int mi = 0; mi < 4; ++mi)
#pragma unroll
      for (int ni = 0; ni < 4; ++ni) {
        const int d = BCOL(ni);
        const int sb = wm * 64 + mi * 16 + g * 4;
        u16x4 w;
#pragma unroll
        for (int q = 0; q < 4; ++q) w[q] = f2bf(acc[mi][ni][q]);
        *(u16x4*)&T[d * 256 + (((sb >> 3) ^ (d & 7)) << 3) + (sb & 7)] = w;
      }
    __syncthreads();
    const int b_ = m0 >> 11, s0l = m0 & 2047;
    const int hh = (n0 - 4096) >> 7;
    const int dd = tid >> 2, part = tid & 3;
    u16* vrow = Vt + ((long)((b_ * 16 + hh) * 128 + dd)) * 2048 + s0l;
#pragma unroll
    for (int cc = 0; cc < 8; ++cc) {
      const int chunk = cc * 4 + part;  // consecutive tids -> consecutive 16B
      s16x8 v = *(const s16x8*)&T[dd * 256 + ((chunk ^ (dd & 7)) << 3)];
      *(s16x8*)&vrow[chunk * 8] = v;
    }
  }
}

// ---------------- Wo GEMM (grid 256 = 1 exact round, f32 out) --------------
__global__ __launch_bounds__(512, 2) void gemm_wo(const u16* __restrict__ A,
                                                  const u16* __restrict__ B,
                                                  float* __restrict__ C) {
  GEMM_V3_BODY(A, B)
#pragma unroll
  for (int mi = 0; mi < 4; ++mi)
#pragma unroll
    for (int ni = 0; ni < 4; ++ni) {
      const int col = n0 + BCOL(ni);
#pragma unroll
      for (int q = 0; q < 4; ++q)
        C[(long)(m0 + wm * 64 + mi * 16 + g * 4 + q) * 2048 + col] =
            acc[mi][ni][q];
    }
}

#undef MFMA_K
#undef READ_K
#undef STAGE_B
#undef STAGE_A
#undef GEMM_V3_BODY
#undef BCOL

// ---------------- Flash attention v8 (verified ~80 us, rounds 15-18) -------
// Double-buffered issue-early staging, one barrier/tile, shuffle-based
// alpha/1-over-l redistribution; mirror strips + jp-complement + XCD pin.
// (v6/v7/v9 restructures all regressed: this 16-waves/CU shape is the
// verified local optimum — latency/occupancy-bound, not pure LDS-BW.)

__device__ __forceinline__ float softmax_swapped(
    f32x4 (&s)[4], float& mi, float& li,
    u16 (&pl)[16][64], int qbase, int k0, int r, int g) {
  const int q = qbase + r;
  const bool edge = (k0 + 63) > qbase;
  float v[16];
#pragma unroll
  for (int kk = 0; kk < 4; kk++)
#pragma unroll
    for (int i = 0; i < 4; i++) {
      float x = s[kk][i] * SCALE2;
      if (edge && (k0 + kk * 16 + g * 4 + i > q)) x = -1e30f;
      v[kk * 4 + i] = x;
    }
  float t8[8], t4[4];
#pragma unroll
  for (int j = 0; j < 8; j++) t8[j] = fmaxf(v[2 * j], v[2 * j + 1]);
#pragma unroll
  for (int j = 0; j < 4; j++) t4[j] = fmaxf(t8[2 * j], t8[2 * j + 1]);
  float mx = fmaxf(fmaxf(t4[0], t4[1]), fmaxf(t4[2], t4[3]));
  mx = fmaxf(mx, __shfl_xor(mx, 16, 64));
  mx = fmaxf(mx, __shfl_xor(mx, 32, 64));
  const float mnew = fmaxf(mi, mx);
  const float a = exp2f(mi - mnew);
  float p[16];
#pragma unroll
  for (int j = 0; j < 16; j++) p[j] = exp2f(v[j] - mnew);
  float s8[8], s4[4];
#pragma unroll
  for (int j = 0; j < 8; j++) s8[j] = p[2 * j] + p[2 * j + 1];
#pragma unroll
  for (int j = 0; j < 4; j++) s4[j] = s8[2 * j] + s8[2 * j + 1];
  float ps = (s4[0] + s4[1]) + (s4[2] + s4[3]);
  ps += __shfl_xor(ps, 16, 64);
  ps += __shfl_xor(ps, 32, 64);
  li = li * a + ps;
  mi = mnew;
  const int sw = (r & 7) << 3;
#pragma unroll
  for (int kk = 0; kk < 4; kk++) {
    u16x4 w;
#pragma unroll
    for (int i = 0; i < 4; i++) w[i] = f2bf(p[kk * 4 + i]);
    *(u16x4*)&pl[r][(kk * 16 + g * 4) ^ sw] = w;
  }
  return a;
}

__global__ __launch_bounds__(512, 4) void attn_kernel(const u16* __restrict__ Q,
                                                      const u16* __restrict__ K,
                                                      const u16* __restrict__ Vt,
                                                      u16* __restrict__ O) {
  __shared__ u16 Klds[2][64 * 128];   // 2 x 16 KB, source-swizzled
  __shared__ u16 Vlds[2][128 * 64];   // 2 x 16 KB, source-swizzled
  __shared__ u16 Plds[8][16][64];     // 16 KB        (total: 80 KB exactly)

  const int tid = threadIdx.x, wave = tid >> 6, lane = tid & 63;
  const int r = lane & 15, g = lane >> 4;
  const int bh = blockIdx.x & 31;   // XCD pin: all blocks of (b,h) on bh%8
  const int jj = blockIdx.x >> 5;   // 0..15
  const int j = (jj < 8) ? jj : 23 - jj;  // complement pairing across rounds
  const int h = bh & 15, b = bh >> 4;
  const bool isB = wave >= 4;
  const int w4 = wave & 3;
  const int strip = isB ? (31 - j) : j;
  const int q0 = strip * 64 + w4 * 16;
  const int nt = 32 - j;            // staged tiles: kt = 0..31-j
  const int lastA = j;              // A-waves compute while kt <= j

  const u16* Qbh = Q + (long)b * SEQ * DM + h * DH;
  const u16* Kbh = K + (long)b * SEQ * DM + h * DH;
  const u16* Vbh = Vt + ((long)(b * NH + h)) * DH * SEQ;

  s16x8 qf[4];
#pragma unroll
  for (int jq = 0; jq < 4; jq++)
    qf[jq] = *(const s16x8*)&Qbh[(long)(q0 + r) * DM + jq * 32 + g * 8];

  f32x4 oacc[8] = {};
  float mi = -1e30f, li = 0.f;

#define STAGE_KV(KT, BU) do {                                                 \
  const int k0_ = (KT) * 64;                                                  \
  _Pragma("unroll") for (int c = 0; c < 2; ++c) {                             \
    const int s = c * 512 + tid;                                              \
    const int krow = s >> 4;                                                  \
    const int kch = (s & 15) ^ (krow & 7);                                    \
    gld_lds16(Kbh + (long)(k0_ + krow) * DM + kch * 8,                        \
              &Klds[BU][(c * 512 + wave * 64) * 8]);                          \
    const int vrow = s >> 3;                                                  \
    const int vch = (s & 7) ^ (vrow & 7);                                     \
    gld_lds16(Vbh + (long)vrow * SEQ + k0_ + vch * 8,                         \
              &Vlds[BU][(c * 512 + wave * 64) * 8]);                          \
  } } while (0)

  STAGE_KV(0, 0);
  __syncthreads();   // drains vmcnt: tile 0 ready

  for (int kt = 0; kt < nt; ++kt) {
    const int bu = kt & 1;
    if (kt + 1 < nt) STAGE_KV(kt + 1, bu ^ 1);  // issue early, wait late
    const int k0 = kt * 64;
    const u16* Kb = Klds[bu];
    const u16* Vb = Vlds[bu];

    const bool active = isB || (kt <= lastA);
    if (active) {
      // ---- QK^T (swapped: K as A-operand) ----
      f32x4 sacc[4] = {};
#pragma unroll
      for (int kk = 0; kk < 4; kk++) {
#pragma unroll
        for (int jq = 0; jq < 4; jq++) {
          s16x8 kf = *(const s16x8*)&Kb[(kk * 16 + r) * 128 +
                                        (((jq * 4 + g) ^ (r & 7)) * 8)];
          sacc[kk] = __builtin_amdgcn_mfma_f32_16x16x32_bf16(kf, qf[jq], sacc[kk], 0, 0, 0);
        }
      }
      float a = softmax_swapped(sacc, mi, li, Plds[wave], q0, k0, r, g);
      f32x4 av;
#pragma unroll
      for (int i = 0; i < 4; i++) av[i] = __shfl(a, g * 4 + i, 64);
#pragma unroll
      for (int f = 0; f < 8; f++)
#pragma unroll
        for (int i = 0; i < 4; i++) oacc[f][i] *= av[i];

      const int sw = (r & 7) << 3;
#pragma unroll
      for (int kc = 0; kc < 2; kc++) {
        s16x8 pf = *(const s16x8*)&Plds[wave][r][(kc * 32 + g * 8) ^ sw];
#pragma unroll
        for (int f = 0; f < 8; f++) {
          s16x8 vf = *(const s16x8*)&Vb[(f * 16 + r) * 64 +
                                        (((kc * 4 + g) ^ (r & 7)) * 8)];
          oacc[f] = __builtin_amdgcn_mfma_f32_16x16x32_bf16(pf, vf, oacc[f], 0, 0, 0);
        }
      }
    }
    // one barrier per tile: next tile's loads drained + WAR for buf reuse
    __syncthreads();
  }
#undef STAGE_KV

  // ---- epilogue: 1/li redistributed via shuffle, direct O write ----
  const float inv = 1.f / li;
  f32x4 iv;
#pragma unroll
  for (int i = 0; i < 4; i++) iv[i] = __shfl(inv, g * 4 + i, 64);
  u16* Obh = O + (long)b * SEQ * DM + h * DH;
#pragma unroll
  for (int f = 0; f < 8; f++)
#pragma unroll
    for (int i = 0; i < 4; i++)
      Obh[(long)(q0 + g * 4 + i) * DM + f * 16 + r] = f2bf(oacc[f][i] * iv[i]);
}

// ---------------- launch ----------------------------------------------------
extern "C" void kernel_launch(void* const* d_in, const int* in_sizes, int n_in,
                              void* d_out, int out_size, void* d_ws, size_t ws_size,
                              hipStream_t stream) {
  const float* x    = (const float*)d_in[0];
  const float* Wq   = (const float*)d_in[1];
  const float* Wk   = (const float*)d_in[2];
  const float* Wv   = (const float*)d_in[3];
  const float* Wo   = (const float*)d_in[4];
  const float* cosT = (const float*)d_in[5];
  const float* sinT = (const float*)d_in[6];
  // d_in[7] = mask: causal, applied analytically.

  if (ws_size < (size_t)134217728) return;  // need 128 MB scratch

  char* ws = (char*)d_ws;
  u16* xb    = (u16*)(ws);               // 16 MB
  u16* Wqkvb = (u16*)(ws + 16777216);    // 24 MB [Wq;Wk;Wv] rows
  u16* Wob   = (u16*)(ws + 41943040);    //  8 MB
  u16* Qlin  = (u16*)(ws + 50331648);    // 16 MB (RoPE'd by QKV GEMM)
  u16* Klin  = (u16*)(ws + 67108864);    // 16 MB (RoPE'd by QKV GEMM)
  u16* Vt    = (u16*)(ws + 100663296);   // 16 MB (transposed by QKV GEMM)
  u16* Olin  = (u16*)(ws + 117440512);   // 16 MB

  cast_all<<<24576, 256, 0, stream>>>(x, Wq, Wk, Wv, Wo, xb, Wqkvb, Wob);

  gemm_qkv8<<<768, 512, 0, stream>>>(xb, Wqkvb, cosT, sinT, Qlin, Klin, Vt);

  attn_kernel<<<512, 512, 0, stream>>>(Qlin, Klin, Vt, Olin);

  gemm_wo<<<256, 512, 0, stream>>>(Olin, Wob, (float*)d_out);
}

// Round 21
// 242.957 us; speedup vs baseline: 1.4938x; 1.0195x over previous
//
#include <hip/hip_runtime.h>

typedef float f32x4 __attribute__((ext_vector_type(4)));
typedef short s16x8 __attribute__((ext_vector_type(8)));
typedef unsigned short u16;
typedef u16 u16x4 __attribute__((ext_vector_type(4)));

#define SEQ 2048
#define BATCH 2
#define NH 16
#define DH 128
#define DM 2048
#define MROWS (BATCH * SEQ)  // 4096

// 1/sqrt(128) * log2(e)  (softmax done in exp2 domain)
__device__ constexpr float SCALE2 = 0.12751879523531f;

__device__ __forceinline__ u16 f2bf(float f) {
  unsigned u = __float_as_uint(f);
  u += 0x7fffu + ((u >> 16) & 1u);
  return (u16)(u >> 16);
}
__device__ __forceinline__ float bf2f(u16 b) {
  return __uint_as_float(((unsigned)b) << 16);
}

__device__ __forceinline__ void gld_lds16(const void* g, void* l) {
  __builtin_amdgcn_global_load_lds(
      (const __attribute__((address_space(1))) unsigned int*)g,
      (__attribute__((address_space(3))) unsigned int*)l, 16, 0, 0);
}

// ---------------- fused cast f32 -> bf16 (x, Wq|Wk|Wv concat, Wo) ----------
__global__ __launch_bounds__(256) void cast_all(const float* __restrict__ x,
                                                const float* __restrict__ Wq,
                                                const float* __restrict__ Wk,
                                                const float* __restrict__ Wv,
                                                const float* __restrict__ Wo,
                                                u16* __restrict__ xb,
                                                u16* __restrict__ Wqkvb,
                                                u16* __restrict__ Wob) {
  long i = (long)blockIdx.x * 256 + threadIdx.x;  // float4-group index
  const float* src;
  u16* dst;
  long off;
  if (i < 2097152)      { src = x;  dst = xb;              off = i; }
  else if (i < 3145728) { src = Wq; dst = Wqkvb;           off = i - 2097152; }
  else if (i < 4194304) { src = Wk; dst = Wqkvb + 4194304; off = i - 3145728; }
  else if (i < 5242880) { src = Wv; dst = Wqkvb + 8388608; off = i - 4194304; }
  else                  { src = Wo; dst = Wob;             off = i - 5242880; }
  float4 v = ((const float4*)src)[off];
  u16x4 o;
  o[0] = f2bf(v.x); o[1] = f2bf(v.y); o[2] = f2bf(v.z); o[3] = f2bf(v.w);
  ((u16x4*)dst)[off] = o;
}

// ============ shared v3 GEMM body: BM=256 x BN=128, kk-split =================
// (verified structure: 110 us for N=6144 / 3 rounds, ~941 TF — the measured
// ceiling for this family; 8-phase, dedup'd and 3-buffer pipelined variants
// all regressed: rounds 7, 8, 19.)
// B-fragment -> output-column mapping permuted: col = wn*32 + (nf&1)*16 +
// (nf>>1)*64 + r (RoPE partner d^64 sits in fragment nf^2, same lane).

#define BCOL(NF) (wn * 32 + ((NF) & 1) * 16 + ((NF) >> 1) * 64 + r)

#define GEMM_V3_BODY(A, B)                                                    \
  __shared__ u16 SMEM[49152]; /* 96 KB */                                     \
  u16 (*Alds)[16384] = (u16(*)[16384])SMEM;          /* 2 x 32 KB */          \
  u16 (*Blds)[8192]  = (u16(*)[8192])(SMEM + 32768); /* 2 x 16 KB */          \
  const int tid = threadIdx.x, wave = tid >> 6, lane = tid & 63;              \
  const int r = lane & 15, g = lane >> 4;                                     \
  const int wm = wave >> 1, wn = wave & 1;                                    \
  const int bid = blockIdx.x;                                                 \
  const int swz = (bid & 7) * (gridDim.x >> 3) + (bid >> 3);                  \
  const int m0 = (swz & 15) * 256;                                            \
  const int n0 = (swz >> 4) * 128;                                            \
  const int lrow = lane >> 3;                                                 \
  const int csrc = (lane & 7) ^ lrow;                                         \
  f32x4 acc[4][4] = {};                                                       \
  s16x8 aF[2][4], bF[2][4];                                                   \
  STAGE_A(0, 0, 0); STAGE_B(0, 0, 0); STAGE_A(0, 1, 0); STAGE_B(0, 1, 0);     \
  STAGE_A(1, 0, 1); STAGE_B(1, 0, 1);                                         \
  asm volatile("s_waitcnt vmcnt(3)" ::: "memory");                            \
  __builtin_amdgcn_s_barrier();                                               \
  for (int t = 0; t < 32; ++t) {                                              \
    const int bt = t & 1, bn = bt ^ 1;                                        \
    const u16* Ab = Alds[bt];                                                 \
    const u16* Bb = Blds[bt];                                                 \
    READ_K(0);                                                                \
    __builtin_amdgcn_sched_barrier(0);                                        \
    READ_K(1);                                                                \
    if (t < 31) { STAGE_A(t + 1, 1, bn); STAGE_B(t + 1, 1, bn); }             \
    asm volatile("s_waitcnt lgkmcnt(8)" ::: "memory");                        \
    __builtin_amdgcn_sched_barrier(0);                                        \
    MFMA_K(0);                                                                \
    asm volatile("s_waitcnt lgkmcnt(0)" ::: "memory");                        \
    __builtin_amdgcn_sched_barrier(0);                                        \
    __builtin_amdgcn_s_barrier();                                             \
    if (t < 30) { STAGE_A(t + 2, 0, bt); STAGE_B(t + 2, 0, bt); }             \
    MFMA_K(1);                                                                \
    if (t < 30)       asm volatile("s_waitcnt vmcnt(3)" ::: "memory");        \
    else if (t == 30) asm volatile("s_waitcnt vmcnt(0)" ::: "memory");        \
    __builtin_amdgcn_s_barrier();                                             \
  }

#define STAGE_A(TA, MH, BUF) do {                                             \
  _Pragma("unroll") for (int i_ = 0; i_ < 2; ++i_) {                          \
    const int row0_ = (MH) * 128 + i_ * 64 + wave * 8;                        \
    gld_lds16(A + (long)(m0 + row0_ + lrow) * 2048 + (TA) * 64 + csrc * 8,    \
              &Alds[BUF][row0_ * 64]);                                        \
  } } while (0)
#define STAGE_B(TA, NHh, BUF) do {                                            \
    const int row0_ = (NHh) * 64 + wave * 8;                                  \
    gld_lds16(B + (long)(n0 + row0_ + lrow) * 2048 + (TA) * 64 + csrc * 8,    \
              &Blds[BUF][row0_ * 64]);                                        \
  } while (0)
#define READ_K(KK) do {                                                       \
  _Pragma("unroll") for (int mf = 0; mf < 4; ++mf) {                          \
    const int arow = wm * 64 + mf * 16 + r;                                   \
    aF[KK][mf] = *(const s16x8*)&Ab[arow * 64 +                               \
                                    ((((KK) * 4 + g) ^ (arow & 7)) * 8)];     \
  }                                                                           \
  _Pragma("unroll") for (int nf = 0; nf < 4; ++nf) {                          \
    const int brow = BCOL(nf);                                                \
    bF[KK][nf] = *(const s16x8*)&Bb[brow * 64 +                               \
                                    ((((KK) * 4 + g) ^ (brow & 7)) * 8)];     \
  } } while (0)
#define MFMA_K(KK) do {                                                       \
  __builtin_amdgcn_s_setprio(1);                                              \
  _Pragma("unroll") for (int mf = 0; mf < 4; ++mf)                            \
    _Pragma("unroll") for (int nf = 0; nf < 4; ++nf)                          \
      acc[mf][nf] = __builtin_amdgcn_mfma_f32_16x16x32_bf16(                  \
          aF[KK][mf], bF[KK][nf], acc[mf][nf], 0, 0, 0);                      \
  __builtin_amdgcn_s_setprio(0);                                              \
} while (0)

// ---------------- QKV GEMM (grid 768 = 3 exact rounds) ---------------------
// Q/K blocks (n0<4096): RoPE applied IN REGISTERS in the epilogue — fragment
// pair (nf, nf+2) holds (d, d+64) in the same lane; cos[d]==cos[d+64] so one
// table read per pair. V blocks (n0>=4096): transpose fused via LDS
// T[128][256] (chunk-swizzled), 64B-coalesced stores into Vt[b,h,d,s].
__global__ __launch_bounds__(512, 2) void gemm_qkv8(const u16* __restrict__ A,
                                                    const u16* __restrict__ B,
                                                    const float* __restrict__ cosT,
                                                    const float* __restrict__ sinT,
                                                    u16* __restrict__ Qo,
                                                    u16* __restrict__ Ko,
                                                    u16* __restrict__ Vt) {
  GEMM_V3_BODY(A, B)
  if (n0 < 4096) {
    // ---- register RoPE epilogue ----
    u16* Cb = (n0 < 2048) ? Qo : Ko;
    const int nc0 = n0 & 2047;
#pragma unroll
    for (int mi = 0; mi < 4; ++mi)
#pragma unroll
      for (int nf = 0; nf < 2; ++nf) {
        const int dlo = wn * 32 + nf * 16 + r;  // in [0,64)
#pragma unroll
        for (int q = 0; q < 4; ++q) {
          const int row = m0 + wm * 64 + mi * 16 + g * 4 + q;
          const int spos = row & 2047;
          const float c = cosT[spos * 128 + dlo];
          const float s = sinT[spos * 128 + dlo];
          const float vlo = acc[mi][nf][q];
          const float vhi = acc[mi][nf + 2][q];
          Cb[(long)row * 2048 + nc0 + dlo]      = f2bf(vlo * c - vhi * s);
          Cb[(long)row * 2048 + nc0 + dlo + 64] = f2bf(vhi * c + vlo * s);
        }
      }
  } else {
    // ---- fused V transpose ----
    u16* T = SMEM;  // 128 x 256 u16 = 64 KB
#pragma unroll
    for (int mi = 0; mi < 4; ++mi)
#pragma unroll
      for (int ni = 0; ni < 4; ++ni) {
        const int d = BCOL(ni);
        const int sb = wm * 64 + mi * 16 + g * 4;
        u16x4 w;
#pragma unroll
        for (int q = 0; q < 4; ++q) w[q] = f2bf(acc[mi][ni][q]);
        *(u16x4*)&T[d * 256 + (((sb >> 3) ^ (d & 7)) << 3) + (sb & 7)] = w;
      }
    __syncthreads();
    const int b_ = m0 >> 11, s0l = m0 & 2047;
    const int hh = (n0 - 4096) >> 7;
    const int dd = tid >> 2, part = tid & 3;
    u16* vrow = Vt + ((long)((b_ * 16 + hh) * 128 + dd)) * 2048 + s0l;
#pragma unroll
    for (int cc = 0; cc < 8; ++cc) {
      const int chunk = cc * 4 + part;  // consecutive tids -> consecutive 16B
      s16x8 v = *(const s16x8*)&T[dd * 256 + ((chunk ^ (dd & 7)) << 3)];
      *(s16x8*)&vrow[chunk * 8] = v;
    }
  }
}

// ---------------- Wo GEMM (grid 256 = 1 exact round, f32 out) --------------
__global__ __launch_bounds__(512, 2) void gemm_wo(const u16* __restrict__ A,
                                                  const u16* __restrict__ B,
                                                  float* __restrict__ C) {
  GEMM_V3_BODY(A, B)
#pragma unroll
  for (int mi = 0; mi < 4; ++mi)
#pragma unroll
    for (int ni = 0; ni < 4; ++ni) {
      const int col = n0 + BCOL(ni);
#pragma unroll
      for (int q = 0; q < 4; ++q)
        C[(long)(m0 + wm * 64 + mi * 16 + g * 4 + q) * 2048 + col] =
            acc[mi][ni][q];
    }
}

#undef MFMA_K
#undef READ_K
#undef STAGE_B
#undef STAGE_A
#undef GEMM_V3_BODY
#undef BCOL

// ---------------- Flash attention v8.1: v8 + T13 defer-max -----------------
// v8 (verified ~80 us) plus RESCALE_THRESHOLD: when the wave-wide score-max
// growth is <= 8 (exp2 domain), keep the old running max — skip the alpha
// exp2, the 4-shuffle broadcast and the 32-mult oacc rescale for that tile.
// P is then bounded by 2^8 = 256 (bf16-representable; f32 accum headroom).
// First tile always rescales (mi = -1e30). Decision is wave-collective
// (__all) because the oacc rescale covers all 16 rows the wave owns.

__device__ __forceinline__ bool softmax_swapped(
    f32x4 (&s)[4], float& mi, float& li, float& a_out,
    u16 (&pl)[16][64], int qbase, int k0, int r, int g) {
  const int q = qbase + r;
  const bool edge = (k0 + 63) > qbase;
  float v[16];
#pragma unroll
  for (int kk = 0; kk < 4; kk++)
#pragma unroll
    for (int i = 0; i < 4; i++) {
      float x = s[kk][i] * SCALE2;
      if (edge && (k0 + kk * 16 + g * 4 + i > q)) x = -1e30f;
      v[kk * 4 + i] = x;
    }
  float t8[8], t4[4];
#pragma unroll
  for (int j = 0; j < 8; j++) t8[j] = fmaxf(v[2 * j], v[2 * j + 1]);
#pragma unroll
  for (int j = 0; j < 4; j++) t4[j] = fmaxf(t8[2 * j], t8[2 * j + 1]);
  float mx = fmaxf(fmaxf(t4[0], t4[1]), fmaxf(t4[2], t4[3]));
  mx = fmaxf(mx, __shfl_xor(mx, 16, 64));
  mx = fmaxf(mx, __shfl_xor(mx, 32, 64));

  // T13: wave-collective defer-max decision (THR = 8 in exp2 domain)
  const bool rescale = !__all(mx - mi <= 8.0f);
  float a = 1.0f;
  if (rescale) {
    const float mnew = fmaxf(mi, mx);
    a = exp2f(mi - mnew);
    mi = mnew;
  }
  float p[16];
#pragma unroll
  for (int j = 0; j < 16; j++) p[j] = exp2f(v[j] - mi);
  float s8[8], s4[4];
#pragma unroll
  for (int j = 0; j < 8; j++) s8[j] = p[2 * j] + p[2 * j + 1];
#pragma unroll
  for (int j = 0; j < 4; j++) s4[j] = s8[2 * j] + s8[2 * j + 1];
  float ps = (s4[0] + s4[1]) + (s4[2] + s4[3]);
  ps += __shfl_xor(ps, 16, 64);
  ps += __shfl_xor(ps, 32, 64);
  li = li * a + ps;
  const int sw = (r & 7) << 3;
#pragma unroll
  for (int kk = 0; kk < 4; kk++) {
    u16x4 w;
#pragma unroll
    for (int i = 0; i < 4; i++) w[i] = f2bf(p[kk * 4 + i]);
    *(u16x4*)&pl[r][(kk * 16 + g * 4) ^ sw] = w;
  }
  a_out = a;
  return rescale;
}

__global__ __launch_bounds__(512, 4) void attn_kernel(const u16* __restrict__ Q,
                                                      const u16* __restrict__ K,
                                                      const u16* __restrict__ Vt,
                                                      u16* __restrict__ O) {
  __shared__ u16 Klds[2][64 * 128];   // 2 x 16 KB, source-swizzled
  __shared__ u16 Vlds[2][128 * 64];   // 2 x 16 KB, source-swizzled
  __shared__ u16 Plds[8][16][64];     // 16 KB        (total: 80 KB exactly)

  const int tid = threadIdx.x, wave = tid >> 6, lane = tid & 63;
  const int r = lane & 15, g = lane >> 4;
  const int bh = blockIdx.x & 31;   // XCD pin: all blocks of (b,h) on bh%8
  const int jj = blockIdx.x >> 5;   // 0..15
  const int j = (jj < 8) ? jj : 23 - jj;  // complement pairing across rounds
  const int h = bh & 15, b = bh >> 4;
  const bool isB = wave >= 4;
  const int w4 = wave & 3;
  const int strip = isB ? (31 - j) : j;
  const int q0 = strip * 64 + w4 * 16;
  const int nt = 32 - j;            // staged tiles: kt = 0..31-j
  const int lastA = j;              // A-waves compute while kt <= j

  const u16* Qbh = Q + (long)b * SEQ * DM + h * DH;
  const u16* Kbh = K + (long)b * SEQ * DM + h * DH;
  const u16* Vbh = Vt + ((long)(b * NH + h)) * DH * SEQ;

  s16x8 qf[4];
#pragma unroll
  for (int jq = 0; jq < 4; jq++)
    qf[jq] = *(const s16x8*)&Qbh[(long)(q0 + r) * DM + jq * 32 + g * 8];

  f32x4 oacc[8] = {};
  float mi = -1e30f, li = 0.f;

#define STAGE_KV(KT, BU) do {                                                 \
  const int k0_ = (KT) * 64;                                                  \
  _Pragma("unroll") for (int c = 0; c < 2; ++c) {                             \
    const int s = c * 512 + tid;                                              \
    const int krow = s >> 4;                                                  \
    const int kch = (s & 15) ^ (krow & 7);                                    \
    gld_lds16(Kbh + (long)(k0_ + krow) * DM + kch * 8,                        \
              &Klds[BU][(c * 512 + wave * 64) * 8]);                          \
    const int vrow = s >> 3;                                                  \
    const int vch = (s & 7) ^ (vrow & 7);                                     \
    gld_lds16(Vbh + (long)vrow * SEQ + k0_ + vch * 8,                         \
              &Vlds[BU][(c * 512 + wave * 64) * 8]);                          \
  } } while (0)

  STAGE_KV(0, 0);
  __syncthreads();   // drains vmcnt: tile 0 ready

  for (int kt = 0; kt < nt; ++kt) {
    const int bu = kt & 1;
    if (kt + 1 < nt) STAGE_KV(kt + 1, bu ^ 1);  // issue early, wait late
    const int k0 = kt * 64;
    const u16* Kb = Klds[bu];
    const u16* Vb = Vlds[bu];

    const bool active = isB || (kt <= lastA);
    if (active) {
      // ---- QK^T (swapped: K as A-operand) ----
      f32x4 sacc[4] = {};
#pragma unroll
      for (int kk = 0; kk < 4; kk++) {
#pragma unroll
        for (int jq = 0; jq < 4; jq++) {
          s16x8 kf = *(const s16x8*)&Kb[(kk * 16 + r) * 128 +
                                        (((jq * 4 + g) ^ (r & 7)) * 8)];
          sacc[kk] = __builtin_amdgcn_mfma_f32_16x16x32_bf16(kf, qf[jq], sacc[kk], 0, 0, 0);
        }
      }
      float a;
      const bool resc = softmax_swapped(sacc, mi, li, a, Plds[wave], q0, k0, r, g);
      if (resc) {
        f32x4 av;
#pragma unroll
        for (int i = 0; i < 4; i++) av[i] = __shfl(a, g * 4 + i, 64);
#pragma unroll
        for (int f = 0; f < 8; f++)
#pragma unroll
          for (int i = 0; i < 4; i++) oacc[f][i] *= av[i];
      }

      const int sw = (r & 7) << 3;
#pragma unroll
      for (int kc = 0; kc < 2; kc++) {
        s16x8 pf = *(const s16x8*)&Plds[wave][r][(kc * 32 + g * 8) ^ sw];
#pragma unroll
        for (int f = 0; f < 8; f++) {
          s16x8 vf = *(const s16x8*)&Vb[(f * 16 + r) * 64 +
                                        (((kc * 4 + g) ^ (r & 7)) * 8)];
          oacc[f] = __builtin_amdgcn_mfma_f32_16x16x32_bf16(pf, vf, oacc[f], 0, 0, 0);
        }
      }
    }
    // one barrier per tile: next tile's loads drained + WAR for buf reuse
    __syncthreads();
  }
#undef STAGE_KV

  // ---- epilogue: 1/li redistributed via shuffle, direct O write ----
  const float inv = 1.f / li;
  f32x4 iv;
#pragma unroll
  for (int i = 0; i < 4; i++) iv[i] = __shfl(inv, g * 4 + i, 64);
  u16* Obh = O + (long)b * SEQ * DM + h * DH;
#pragma unroll
  for (int f = 0; f < 8; f++)
#pragma unroll
    for (int i = 0; i < 4; i++)
      Obh[(long)(q0 + g * 4 + i) * DM + f * 16 + r] = f2bf(oacc[f][i] * iv[i]);
}

// ---------------- launch ----------------------------------------------------
extern "C" void kernel_launch(void* const* d_in, const int* in_sizes, int n_in,
                              void* d_out, int out_size, void* d_ws, size_t ws_size,
                              hipStream_t stream) {
  const float* x    = (const float*)d_in[0];
  const float* Wq   = (const float*)d_in[1];
  const float* Wk   = (const float*)d_in[2];
  const float* Wv   = (const float*)d_in[3];
  const float* Wo   = (const float*)d_in[4];
  const float* cosT = (const float*)d_in[5];
  const float* sinT = (const float*)d_in[6];
  // d_in[7] = mask: causal, applied analytically.

  if (ws_size < (size_t)134217728) return;  // need 128 MB scratch

  char* ws = (char*)d_ws;
  u16* xb    = (u16*)(ws);               // 16 MB
  u16* Wqkvb = (u16*)(ws + 16777216);    // 24 MB [Wq;Wk;Wv] rows
  u16* Wob   = (u16*)(ws + 41943040);    //  8 MB
  u16* Qlin  = (u16*)(ws + 50331648);    // 16 MB (RoPE'd by QKV GEMM)
  u16* Klin  = (u16*)(ws + 67108864);    // 16 MB (RoPE'd by QKV GEMM)
  u16* Vt    = (u16*)(ws + 100663296);   // 16 MB (transposed by QKV GEMM)
  u16* Olin  = (u16*)(ws + 117440512);   // 16 MB

  cast_all<<<24576, 256, 0, stream>>>(x, Wq, Wk, Wv, Wo, xb, Wqkvb, Wob);

  gemm_qkv8<<<768, 512, 0, stream>>>(xb, Wqkvb, cosT, sinT, Qlin, Klin, Vt);

  attn_kernel<<<512, 512, 0, stream>>>(Qlin, Klin, Vt, Olin);

  gemm_wo<<<256, 512, 0, stream>>>(Olin, Wob, (float*)d_out);
}

// Round 22
// 238.565 us; speedup vs baseline: 1.5213x; 1.0184x over previous
//
#include <hip/hip_runtime.h>

typedef float f32x4 __attribute__((ext_vector_type(4)));
typedef short s16x8 __attribute__((ext_vector_type(8)));
typedef unsigned short u16;
typedef u16 u16x4 __attribute__((ext_vector_type(4)));

#define SEQ 2048
#define BATCH 2
#define NH 16
#define DH 128
#define DM 2048
#define MROWS (BATCH * SEQ)  // 4096

// 1/sqrt(128) * log2(e)  (softmax done in exp2 domain)
__device__ constexpr float SCALE2 = 0.12751879523531f;

__device__ __forceinline__ u16 f2bf(float f) {
  unsigned u = __float_as_uint(f);
  u += 0x7fffu + ((u >> 16) & 1u);
  return (u16)(u >> 16);
}
__device__ __forceinline__ float bf2f(u16 b) {
  return __uint_as_float(((unsigned)b) << 16);
}

__device__ __forceinline__ void gld_lds16(const void* g, void* l) {
  __builtin_amdgcn_global_load_lds(
      (const __attribute__((address_space(1))) unsigned int*)g,
      (__attribute__((address_space(3))) unsigned int*)l, 16, 0, 0);
}

// ---------------- fused cast f32 -> bf16 (x, Wq|Wk|Wv concat, Wo) ----------
__global__ __launch_bounds__(256) void cast_all(const float* __restrict__ x,
                                                const float* __restrict__ Wq,
                                                const float* __restrict__ Wk,
                                                const float* __restrict__ Wv,
                                                const float* __restrict__ Wo,
                                                u16* __restrict__ xb,
                                                u16* __restrict__ Wqkvb,
                                                u16* __restrict__ Wob) {
  long i = (long)blockIdx.x * 256 + threadIdx.x;  // float4-group index
  const float* src;
  u16* dst;
  long off;
  if (i < 2097152)      { src = x;  dst = xb;              off = i; }
  else if (i < 3145728) { src = Wq; dst = Wqkvb;           off = i - 2097152; }
  else if (i < 4194304) { src = Wk; dst = Wqkvb + 4194304; off = i - 3145728; }
  else if (i < 5242880) { src = Wv; dst = Wqkvb + 8388608; off = i - 4194304; }
  else                  { src = Wo; dst = Wob;             off = i - 5242880; }
  float4 v = ((const float4*)src)[off];
  u16x4 o;
  o[0] = f2bf(v.x); o[1] = f2bf(v.y); o[2] = f2bf(v.z); o[3] = f2bf(v.w);
  ((u16x4*)dst)[off] = o;
}

// ============ shared v3 GEMM body: BM=256 x BN=128, kk-split =================
// (verified structure: 110 us for N=6144 / 3 rounds, ~941 TF — the measured
// ceiling for this family; 8-phase, dedup'd and 3-buffer pipelined variants
// all regressed: rounds 7, 8, 19.)
// B-fragment -> output-column mapping permuted: col = wn*32 + (nf&1)*16 +
// (nf>>1)*64 + r (RoPE partner d^64 sits in fragment nf^2, same lane).

#define BCOL(NF) (wn * 32 + ((NF) & 1) * 16 + ((NF) >> 1) * 64 + r)

#define GEMM_V3_BODY(A, B)                                                    \
  __shared__ u16 SMEM[49152]; /* 96 KB */                                     \
  u16 (*Alds)[16384] = (u16(*)[16384])SMEM;          /* 2 x 32 KB */          \
  u16 (*Blds)[8192]  = (u16(*)[8192])(SMEM + 32768); /* 2 x 16 KB */          \
  const int tid = threadIdx.x, wave = tid >> 6, lane = tid & 63;              \
  const int r = lane & 15, g = lane >> 4;                                     \
  const int wm = wave >> 1, wn = wave & 1;                                    \
  const int bid = blockIdx.x;                                                 \
  const int swz = (bid & 7) * (gridDim.x >> 3) + (bid >> 3);                  \
  const int m0 = (swz & 15) * 256;                                            \
  const int n0 = (swz >> 4) * 128;                                            \
  const int lrow = lane >> 3;                                                 \
  const int csrc = (lane & 7) ^ lrow;                                         \
  f32x4 acc[4][4] = {};                                                       \
  s16x8 aF[2][4], bF[2][4];                                                   \
  STAGE_A(0, 0, 0); STAGE_B(0, 0, 0); STAGE_A(0, 1, 0); STAGE_B(0, 1, 0);     \
  STAGE_A(1, 0, 1); STAGE_B(1, 0, 1);                                         \
  asm volatile("s_waitcnt vmcnt(3)" ::: "memory");                            \
  __builtin_amdgcn_s_barrier();                                               \
  for (int t = 0; t < 32; ++t) {                                              \
    const int bt = t & 1, bn = bt ^ 1;                                        \
    const u16* Ab = Alds[bt];                                                 \
    const u16* Bb = Blds[bt];                                                 \
    READ_K(0);                                                                \
    __builtin_amdgcn_sched_barrier(0);                                        \
    READ_K(1);                                                                \
    if (t < 31) { STAGE_A(t + 1, 1, bn); STAGE_B(t + 1, 1, bn); }             \
    asm volatile("s_waitcnt lgkmcnt(8)" ::: "memory");                        \
    __builtin_amdgcn_sched_barrier(0);                                        \
    MFMA_K(0);                                                                \
    asm volatile("s_waitcnt lgkmcnt(0)" ::: "memory");                        \
    __builtin_amdgcn_sched_barrier(0);                                        \
    __builtin_amdgcn_s_barrier();                                             \
    if (t < 30) { STAGE_A(t + 2, 0, bt); STAGE_B(t + 2, 0, bt); }             \
    MFMA_K(1);                                                                \
    if (t < 30)       asm volatile("s_waitcnt vmcnt(3)" ::: "memory");        \
    else if (t == 30) asm volatile("s_waitcnt vmcnt(0)" ::: "memory");        \
    __builtin_amdgcn_s_barrier();                                             \
  }

#define STAGE_A(TA, MH, BUF) do {                                             \
  _Pragma("unroll") for (int i_ = 0; i_ < 2; ++i_) {                          \
    const int row0_ = (MH) * 128 + i_ * 64 + wave * 8;                        \
    gld_lds16(A + (long)(m0 + row0_ + lrow) * 2048 + (TA) * 64 + csrc * 8,    \
              &Alds[BUF][row0_ * 64]);                                        \
  } } while (0)
#define STAGE_B(TA, NHh, BUF) do {                                            \
    const int row0_ = (NHh) * 64 + wave * 8;                                  \
    gld_lds16(B + (long)(n0 + row0_ + lrow) * 2048 + (TA) * 64 + csrc * 8,    \
              &Blds[BUF][row0_ * 64]);                                        \
  } while (0)
#define READ_K(KK) do {                                                       \
  _Pragma("unroll") for (int mf = 0; mf < 4; ++mf) {                          \
    const int arow = wm * 64 + mf * 16 + r;                                   \
    aF[KK][mf] = *(const s16x8*)&Ab[arow * 64 +                               \
                                    ((((KK) * 4 + g) ^ (arow & 7)) * 8)];     \
  }                                                                           \
  _Pragma("unroll") for (int nf = 0; nf < 4; ++nf) {                          \
    const int brow = BCOL(nf);                                                \
    bF[KK][nf] = *(const s16x8*)&Bb[brow * 64 +                               \
                                    ((((KK) * 4 + g) ^ (brow & 7)) * 8)];     \
  } } while (0)
#define MFMA_K(KK) do {                                                       \
  __builtin_amdgcn_s_setprio(1);                                              \
  _Pragma("unroll") for (int mf = 0; mf < 4; ++mf)                            \
    _Pragma("unroll") for (int nf = 0; nf < 4; ++nf)                          \
      acc[mf][nf] = __builtin_amdgcn_mfma_f32_16x16x32_bf16(                  \
          aF[KK][mf], bF[KK][nf], acc[mf][nf], 0, 0, 0);                      \
  __builtin_amdgcn_s_setprio(0);                                              \
} while (0)

// ---------------- QKV GEMM (grid 768 = 3 exact rounds) ---------------------
// Q/K blocks (n0<4096): RoPE applied IN REGISTERS in the epilogue — fragment
// pair (nf, nf+2) holds (d, d+64) in the same lane; cos[d]==cos[d+64] so one
// table read per pair. V blocks (n0>=4096): transpose fused via LDS
// T[128][256] (chunk-swizzled), 64B-coalesced stores into Vt[b,h,d,s].
__global__ __launch_bounds__(512, 2) void gemm_qkv8(const u16* __restrict__ A,
                                                    const u16* __restrict__ B,
                                                    const float* __restrict__ cosT,
                                                    const float* __restrict__ sinT,
                                                    u16* __restrict__ Qo,
                                                    u16* __restrict__ Ko,
                                                    u16* __restrict__ Vt) {
  GEMM_V3_BODY(A, B)
  if (n0 < 4096) {
    // ---- register RoPE epilogue ----
    u16* Cb = (n0 < 2048) ? Qo : Ko;
    const int nc0 = n0 & 2047;
#pragma unroll
    for (int mi = 0; mi < 4; ++mi)
#pragma unroll
      for (int nf = 0; nf < 2; ++nf) {
        const int dlo = wn * 32 + nf * 16 + r;  // in [0,64)
#pragma unroll
        for (int q = 0; q < 4; ++q) {
          const int row = m0 + wm * 64 + mi * 16 + g * 4 + q;
          const int spos = row & 2047;
          const float c = cosT[spos * 128 + dlo];
          const float s = sinT[spos * 128 + dlo];
          const float vlo = acc[mi][nf][q];
          const float vhi = acc[mi][nf + 2][q];
          Cb[(long)row * 2048 + nc0 + dlo]      = f2bf(vlo * c - vhi * s);
          Cb[(long)row * 2048 + nc0 + dlo + 64] = f2bf(vhi * c + vlo * s);
        }
      }
  } else {
    // ---- fused V transpose ----
    u16* T = SMEM;  // 128 x 256 u16 = 64 KB
#pragma unroll
    for (int mi = 0; mi < 4; ++mi)
#pragma unroll
      for (int ni = 0; ni < 4; ++ni) {
        const int d = BCOL(ni);
        const int sb = wm * 64 + mi * 16 + g * 4;
        u16x4 w;
#pragma unroll
        for (int q = 0; q < 4; ++q) w[q] = f2bf(acc[mi][ni][q]);
        *(u16x4*)&T[d * 256 + (((sb >> 3) ^ (d & 7)) << 3) + (sb & 7)] = w;
      }
    __syncthreads();
    const int b_ = m0 >> 11, s0l = m0 & 2047;
    const int hh = (n0 - 4096) >> 7;
    const int dd = tid >> 2, part = tid & 3;
    u16* vrow = Vt + ((long)((b_ * 16 + hh) * 128 + dd)) * 2048 + s0l;
#pragma unroll
    for (int cc = 0; cc < 8; ++cc) {
      const int chunk = cc * 4 + part;  // consecutive tids -> consecutive 16B
      s16x8 v = *(const s16x8*)&T[dd * 256 + ((chunk ^ (dd & 7)) << 3)];
      *(s16x8*)&vrow[chunk * 8] = v;
    }
  }
}

// ---------------- Wo GEMM (grid 256 = 1 exact round, f32 out) --------------
__global__ __launch_bounds__(512, 2) void gemm_wo(const u16* __restrict__ A,
                                                  const u16* __restrict__ B,
                                                  float* __restrict__ C) {
  GEMM_V3_BODY(A, B)
#pragma unroll
  for (int mi = 0; mi < 4; ++mi)
#pragma unroll
    for (int ni = 0; ni < 4; ++ni) {
      const int col = n0 + BCOL(ni);
#pragma unroll
      for (int q = 0; q < 4; ++q)
        C[(long)(m0 + wm * 64 + mi * 16 + g * 4 + q) * 2048 + col] =
            acc[mi][ni][q];
    }
}

#undef MFMA_K
#undef READ_K
#undef STAGE_B
#undef STAGE_A
#undef GEMM_V3_BODY
#undef BCOL

// ---------------- Flash attention v8.2: v8.1 + T5 setprio ------------------
// v8 (verified ~75 us with T13 defer-max) plus s_setprio(1) around the QK^T
// and PV MFMA clusters. Regime matches m191's +4-7%: 2 independent blocks/CU
// whose tile loops are mutually unsynchronized — priority keeps one block's
// MFMA stream fed while the other block runs its VALU softmax chain.

__device__ __forceinline__ bool softmax_swapped(
    f32x4 (&s)[4], float& mi, float& li, float& a_out,
    u16 (&pl)[16][64], int qbase, int k0, int r, int g) {
  const int q = qbase + r;
  const bool edge = (k0 + 63) > qbase;
  float v[16];
#pragma unroll
  for (int kk = 0; kk < 4; kk++)
#pragma unroll
    for (int i = 0; i < 4; i++) {
      float x = s[kk][i] * SCALE2;
      if (edge && (k0 + kk * 16 + g * 4 + i > q)) x = -1e30f;
      v[kk * 4 + i] = x;
    }
  float t8[8], t4[4];
#pragma unroll
  for (int j = 0; j < 8; j++) t8[j] = fmaxf(v[2 * j], v[2 * j + 1]);
#pragma unroll
  for (int j = 0; j < 4; j++) t4[j] = fmaxf(t8[2 * j], t8[2 * j + 1]);
  float mx = fmaxf(fmaxf(t4[0], t4[1]), fmaxf(t4[2], t4[3]));
  mx = fmaxf(mx, __shfl_xor(mx, 16, 64));
  mx = fmaxf(mx, __shfl_xor(mx, 32, 64));

  // T13: wave-collective defer-max decision (THR = 8 in exp2 domain)
  const bool rescale = !__all(mx - mi <= 8.0f);
  float a = 1.0f;
  if (rescale) {
    const float mnew = fmaxf(mi, mx);
    a = exp2f(mi - mnew);
    mi = mnew;
  }
  float p[16];
#pragma unroll
  for (int j = 0; j < 16; j++) p[j] = exp2f(v[j] - mi);
  float s8[8], s4[4];
#pragma unroll
  for (int j = 0; j < 8; j++) s8[j] = p[2 * j] + p[2 * j + 1];
#pragma unroll
  for (int j = 0; j < 4; j++) s4[j] = s8[2 * j] + s8[2 * j + 1];
  float ps = (s4[0] + s4[1]) + (s4[2] + s4[3]);
  ps += __shfl_xor(ps, 16, 64);
  ps += __shfl_xor(ps, 32, 64);
  li = li * a + ps;
  const int sw = (r & 7) << 3;
#pragma unroll
  for (int kk = 0; kk < 4; kk++) {
    u16x4 w;
#pragma unroll
    for (int i = 0; i < 4; i++) w[i] = f2bf(p[kk * 4 + i]);
    *(u16x4*)&pl[r][(kk * 16 + g * 4) ^ sw] = w;
  }
  a_out = a;
  return rescale;
}

__global__ __launch_bounds__(512, 4) void attn_kernel(const u16* __restrict__ Q,
                                                      const u16* __restrict__ K,
                                                      const u16* __restrict__ Vt,
                                                      u16* __restrict__ O) {
  __shared__ u16 Klds[2][64 * 128];   // 2 x 16 KB, source-swizzled
  __shared__ u16 Vlds[2][128 * 64];   // 2 x 16 KB, source-swizzled
  __shared__ u16 Plds[8][16][64];     // 16 KB        (total: 80 KB exactly)

  const int tid = threadIdx.x, wave = tid >> 6, lane = tid & 63;
  const int r = lane & 15, g = lane >> 4;
  const int bh = blockIdx.x & 31;   // XCD pin: all blocks of (b,h) on bh%8
  const int jj = blockIdx.x >> 5;   // 0..15
  const int j = (jj < 8) ? jj : 23 - jj;  // complement pairing across rounds
  const int h = bh & 15, b = bh >> 4;
  const bool isB = wave >= 4;
  const int w4 = wave & 3;
  const int strip = isB ? (31 - j) : j;
  const int q0 = strip * 64 + w4 * 16;
  const int nt = 32 - j;            // staged tiles: kt = 0..31-j
  const int lastA = j;              // A-waves compute while kt <= j

  const u16* Qbh = Q + (long)b * SEQ * DM + h * DH;
  const u16* Kbh = K + (long)b * SEQ * DM + h * DH;
  const u16* Vbh = Vt + ((long)(b * NH + h)) * DH * SEQ;

  s16x8 qf[4];
#pragma unroll
  for (int jq = 0; jq < 4; jq++)
    qf[jq] = *(const s16x8*)&Qbh[(long)(q0 + r) * DM + jq * 32 + g * 8];

  f32x4 oacc[8] = {};
  float mi = -1e30f, li = 0.f;

#define STAGE_KV(KT, BU) do {                                                 \
  const int k0_ = (KT) * 64;                                                  \
  _Pragma("unroll") for (int c = 0; c < 2; ++c) {                             \
    const int s = c * 512 + tid;                                              \
    const int krow = s >> 4;                                                  \
    const int kch = (s & 15) ^ (krow & 7);                                    \
    gld_lds16(Kbh + (long)(k0_ + krow) * DM + kch * 8,                        \
              &Klds[BU][(c * 512 + wave * 64) * 8]);                          \
    const int vrow = s >> 3;                                                  \
    const int vch = (s & 7) ^ (vrow & 7);                                     \
    gld_lds16(Vbh + (long)vrow * SEQ + k0_ + vch * 8,                         \
              &Vlds[BU][(c * 512 + wave * 64) * 8]);                          \
  } } while (0)

  STAGE_KV(0, 0);
  __syncthreads();   // drains vmcnt: tile 0 ready

  for (int kt = 0; kt < nt; ++kt) {
    const int bu = kt & 1;
    if (kt + 1 < nt) STAGE_KV(kt + 1, bu ^ 1);  // issue early, wait late
    const int k0 = kt * 64;
    const u16* Kb = Klds[bu];
    const u16* Vb = Vlds[bu];

    const bool active = isB || (kt <= lastA);
    if (active) {
      // ---- QK^T (swapped: K as A-operand), T5 priority boost ----
      f32x4 sacc[4] = {};
      __builtin_amdgcn_s_setprio(1);
#pragma unroll
      for (int kk = 0; kk < 4; kk++) {
#pragma unroll
        for (int jq = 0; jq < 4; jq++) {
          s16x8 kf = *(const s16x8*)&Kb[(kk * 16 + r) * 128 +
                                        (((jq * 4 + g) ^ (r & 7)) * 8)];
          sacc[kk] = __builtin_amdgcn_mfma_f32_16x16x32_bf16(kf, qf[jq], sacc[kk], 0, 0, 0);
        }
      }
      __builtin_amdgcn_s_setprio(0);
      float a;
      const bool resc = softmax_swapped(sacc, mi, li, a, Plds[wave], q0, k0, r, g);
      if (resc) {
        f32x4 av;
#pragma unroll
        for (int i = 0; i < 4; i++) av[i] = __shfl(a, g * 4 + i, 64);
#pragma unroll
        for (int f = 0; f < 8; f++)
#pragma unroll
          for (int i = 0; i < 4; i++) oacc[f][i] *= av[i];
      }

      const int sw = (r & 7) << 3;
      // ---- PV, T5 priority boost ----
      __builtin_amdgcn_s_setprio(1);
#pragma unroll
      for (int kc = 0; kc < 2; kc++) {
        s16x8 pf = *(const s16x8*)&Plds[wave][r][(kc * 32 + g * 8) ^ sw];
#pragma unroll
        for (int f = 0; f < 8; f++) {
          s16x8 vf = *(const s16x8*)&Vb[(f * 16 + r) * 64 +
                                        (((kc * 4 + g) ^ (r & 7)) * 8)];
          oacc[f] = __builtin_amdgcn_mfma_f32_16x16x32_bf16(pf, vf, oacc[f], 0, 0, 0);
        }
      }
      __builtin_amdgcn_s_setprio(0);
    }
    // one barrier per tile: next tile's loads drained + WAR for buf reuse
    __syncthreads();
  }
#undef STAGE_KV

  // ---- epilogue: 1/li redistributed via shuffle, direct O write ----
  const float inv = 1.f / li;
  f32x4 iv;
#pragma unroll
  for (int i = 0; i < 4; i++) iv[i] = __shfl(inv, g * 4 + i, 64);
  u16* Obh = O + (long)b * SEQ * DM + h * DH;
#pragma unroll
  for (int f = 0; f < 8; f++)
#pragma unroll
    for (int i = 0; i < 4; i++)
      Obh[(long)(q0 + g * 4 + i) * DM + f * 16 + r] = f2bf(oacc[f][i] * iv[i]);
}

// ---------------- launch ----------------------------------------------------
extern "C" void kernel_launch(void* const* d_in, const int* in_sizes, int n_in,
                              void* d_out, int out_size, void* d_ws, size_t ws_size,
                              hipStream_t stream) {
  const float* x    = (const float*)d_in[0];
  const float* Wq   = (const float*)d_in[1];
  const float* Wk   = (const float*)d_in[2];
  const float* Wv   = (const float*)d_in[3];
  const float* Wo   = (const float*)d_in[4];
  const float* cosT = (const float*)d_in[5];
  const float* sinT = (const float*)d_in[6];
  // d_in[7] = mask: causal, applied analytically.

  if (ws_size < (size_t)134217728) return;  // need 128 MB scratch

  char* ws = (char*)d_ws;
  u16* xb    = (u16*)(ws);               // 16 MB
  u16* Wqkvb = (u16*)(ws + 16777216);    // 24 MB [Wq;Wk;Wv] rows
  u16* Wob   = (u16*)(ws + 41943040);    //  8 MB
  u16* Qlin  = (u16*)(ws + 50331648);    // 16 MB (RoPE'd by QKV GEMM)
  u16* Klin  = (u16*)(ws + 67108864);    // 16 MB (RoPE'd by QKV GEMM)
  u16* Vt    = (u16*)(ws + 100663296);   // 16 MB (transposed by QKV GEMM)
  u16* Olin  = (u16*)(ws + 117440512);   // 16 MB

  cast_all<<<24576, 256, 0, stream>>>(x, Wq, Wk, Wv, Wo, xb, Wqkvb, Wob);

  gemm_qkv8<<<768, 512, 0, stream>>>(xb, Wqkvb, cosT, sinT, Qlin, Klin, Vt);

  attn_kernel<<<512, 512, 0, stream>>>(Qlin, Klin, Vt, Olin);

  gemm_wo<<<256, 512, 0, stream>>>(Olin, Wob, (float*)d_out);
}